// Round 1
// baseline (1170.879 us; speedup 1.0000x reference)
//
#include <hip/hip_runtime.h>
#include <cstdint>
#include <cstddef>

typedef short v8s __attribute__((ext_vector_type(8)));
typedef float v4f __attribute__((ext_vector_type(4)));

#define NG   2000
#define IND  4000
#define HDIM 256
#define OUTW 4256   // IND + HDIM

// ---------------- helpers ----------------
__device__ __forceinline__ unsigned short f2bf(float f) {
  unsigned a = __builtin_bit_cast(unsigned, f);
  a += 0x7fffu + ((a >> 16) & 1u);
  return (unsigned short)(a >> 16);
}
__device__ __forceinline__ unsigned pk2bf(float lo, float hi) {
  unsigned a = __builtin_bit_cast(unsigned, lo);
  unsigned b = __builtin_bit_cast(unsigned, hi);
  a += 0x7fffu + ((a >> 16) & 1u);
  b += 0x7fffu + ((b >> 16) & 1u);
  return (a >> 16) | (b & 0xffff0000u);
}
__device__ __forceinline__ void async16(const void* g, void* l) {
  __builtin_amdgcn_global_load_lds(
      (const __attribute__((address_space(1))) unsigned int*)g,
      (__attribute__((address_space(3))) unsigned int*)l, 16, 0, 0);
}

// ---------------- prep: transpose 4 weight matrices [4000,256] -> bf16 [256,4000] ----------------
__global__ void k_transpose(const float* __restrict__ w1, const float* __restrict__ wa1,
                            const float* __restrict__ wd, const float* __restrict__ wr,
                            unsigned short* __restrict__ ws0) {
  __shared__ float tl[32][33];
  int mat = blockIdx.z;
  const float* src = (mat == 0) ? wa1 : (mat == 1) ? w1 : (mat == 2) ? wd : wr;
  unsigned short* dst = ws0 + (size_t)mat * 1024000;  // 2,048,000 B each
  int j0 = blockIdx.x * 32, c0 = blockIdx.y * 32;
  int tx = threadIdx.x, ty = threadIdx.y;
  for (int jj = ty; jj < 32; jj += 8)
    tl[jj][tx] = src[(size_t)(j0 + jj) * HDIM + c0 + tx];
  __syncthreads();
  for (int cc = ty; cc < 32; cc += 8)
    dst[(size_t)(c0 + cc) * IND + j0 + tx] = f2bf(tl[tx][cc]);
}

// ---------------- enc copy to out + bf16 cast ----------------
__global__ void k_enc_copy(const float* __restrict__ enc, float* __restrict__ out,
                           unsigned short* __restrict__ eb) {
  int c = blockIdx.x * 256 + threadIdx.x;
  int b = blockIdx.y;
  if (c < IND) {
    float v = enc[(size_t)b * IND + c];
    out[(size_t)b * OUTW + c] = v;
    eb[(size_t)b * IND + c] = f2bf(v);
  }
}

// ---------------- attention logits: fused gather+log + MFMA GEMM + tanh·Wa2 ----------------
// grid 512 (64 rows each), block 256. C[m=wcol 256][n=row 64], wave w owns wcols [w*64, w*64+64)
__global__ void __launch_bounds__(256) k_logits(
    const int* __restrict__ nidx1, const int* __restrict__ nidx2,
    const float* __restrict__ sp, const float* __restrict__ un,
    const unsigned short* __restrict__ Wa1T,
    const float* __restrict__ ba1, const float* __restrict__ Wa2,
    const float* __restrict__ ba2, float* __restrict__ logits) {
  __shared__ __align__(16) unsigned short a_tile[256 * 32];
  __shared__ __align__(16) unsigned short b_tile[64 * 32];
  __shared__ int scell[64];
  __shared__ float red[4][64];

  const int t = threadIdx.x;
  const int wave = t >> 6, lane = t & 63;
  const int row_base = blockIdx.x * 64;

  if (t < 64) {
    int r = row_base + t;
    scell[t] = (r < 16384) ? nidx1[r] : nidx2[r - 16384];
  }
  __syncthreads();

  const int lrow = lane & 15, kgrp = lane >> 4;
  const int brow = t >> 2, bpart = t & 3;
  const size_t cellbase = (size_t)scell[brow] * NG;

  v4f acc[4][4];
#pragma unroll
  for (int i = 0; i < 4; i++)
#pragma unroll
    for (int j = 0; j < 4; j++) acc[i][j] = (v4f)0.f;

  for (int kt = 0; kt < 125; ++kt) {
    // A tile: Wa1T[256][kt*32..+32] via async DMA (1024 16B chunks)
#pragma unroll
    for (int j = 0; j < 4; ++j) {
      int c = (wave * 4 + j) * 64 + lane;
      int wcol = c >> 2, part = c & 3;
      async16(Wa1T + (size_t)wcol * IND + kt * 32 + part * 8,
              (char*)a_tile + (size_t)c * 16);
    }
    // B tile: gather + log + bf16 pack (8 cols per thread; 2000 % 8 == 0, no straddle)
    {
      int col0 = kt * 32 + bpart * 8;
      const float* src = (col0 < NG) ? (sp + cellbase + col0) : (un + cellbase + (col0 - NG));
      float4 v0 = reinterpret_cast<const float4*>(src)[0];
      float4 v1 = reinterpret_cast<const float4*>(src)[1];
      uint4 pk;
      pk.x = pk2bf(__logf(0.01f + v0.x), __logf(0.01f + v0.y));
      pk.y = pk2bf(__logf(0.01f + v0.z), __logf(0.01f + v0.w));
      pk.z = pk2bf(__logf(0.01f + v1.x), __logf(0.01f + v1.y));
      pk.w = pk2bf(__logf(0.01f + v1.z), __logf(0.01f + v1.w));
      reinterpret_cast<uint4*>(b_tile)[t] = pk;
    }
    __syncthreads();
    v8s bf[4];
#pragma unroll
    for (int nt = 0; nt < 4; nt++)
      bf[nt] = *reinterpret_cast<const v8s*>(&b_tile[(nt * 16 + lrow) * 32 + kgrp * 8]);
#pragma unroll
    for (int mt = 0; mt < 4; mt++) {
      v8s af = *reinterpret_cast<const v8s*>(&a_tile[(wave * 64 + mt * 16 + lrow) * 32 + kgrp * 8]);
#pragma unroll
      for (int nt = 0; nt < 4; nt++)
        acc[mt][nt] = __builtin_amdgcn_mfma_f32_16x16x32_bf16(af, bf[nt], acc[mt][nt], 0, 0, 0);
    }
    __syncthreads();
  }

  // epilogue: logit[row] = sum_wcol tanh(h + ba1)·Wa2 + ba2
  float partial[4] = {0.f, 0.f, 0.f, 0.f};
#pragma unroll
  for (int mt = 0; mt < 4; mt++) {
#pragma unroll
    for (int r = 0; r < 4; r++) {
      int wcol = wave * 64 + mt * 16 + kgrp * 4 + r;
      float bb = ba1[wcol], wv = Wa2[wcol];
#pragma unroll
      for (int nt = 0; nt < 4; nt++) {
        float h = acc[mt][nt][r] + bb;
        float th = 1.f - 2.f / (1.f + __expf(2.f * h));  // NaN/overflow-safe tanh
        partial[nt] += th * wv;
      }
    }
  }
#pragma unroll
  for (int nt = 0; nt < 4; nt++) {
    float p = partial[nt];
    p += __shfl_xor(p, 16);
    p += __shfl_xor(p, 32);
    if (lane < 16) red[wave][nt * 16 + lane] = p;
  }
  __syncthreads();
  if (t < 64)
    logits[row_base + t] = red[0][t] + red[1][t] + red[2][t] + red[3][t] + ba2[0];
}

// ---------------- softmax over K=16 + weight renormalize ----------------
__global__ void k_softmax(const float* __restrict__ logits,
                          const float* __restrict__ nw1, const float* __restrict__ nw2,
                          float* __restrict__ wnorm, float* __restrict__ wsum) {
  int t = threadIdx.x;
  int gb = blockIdx.x * 16 + (t >> 4);
  int k = t & 15;
  float lg = logits[gb * 16 + k];
  float mx = lg;
#pragma unroll
  for (int m = 1; m < 16; m <<= 1) mx = fmaxf(mx, __shfl_xor(mx, m));
  float e = __expf(lg - mx);
  float s = e;
#pragma unroll
  for (int m = 1; m < 16; m <<= 1) s += __shfl_xor(s, m);
  float att = e / s;
  float nw = (gb < 1024) ? nw1[gb * 16 + k] : nw2[(gb - 1024) * 16 + k];
  float w = nw * att;
  float S = w;
#pragma unroll
  for (int m = 1; m < 16; m <<= 1) S += __shfl_xor(S, m);
  wnorm[gb * 16 + k] = w / (S + 1e-12f);
  if (k == 0) wsum[gb] = S / (S + 1e-12f);
}

// ---------------- weighted sum gather: x (bf16) and diff = x - wsum*enc (bf16) ----------------
__global__ void __launch_bounds__(256) k_wsum(
    const int* __restrict__ nidx1, const int* __restrict__ nidx2,
    const float* __restrict__ sp, const float* __restrict__ un,
    const float* __restrict__ enc,
    const float* __restrict__ wnorm, const float* __restrict__ wsum,
    unsigned short* __restrict__ xb, unsigned short* __restrict__ db) {
  __shared__ size_t cb[16];
  __shared__ float wv[16];
  int gb = blockIdx.x, t = threadIdx.x;
  int g = gb >> 10, b = gb & 1023;
  if (t < 16) {
    int cell = (g == 0 ? nidx1 : nidx2)[b * 16 + t];
    cb[t] = (size_t)cell * NG;
    wv[t] = wnorm[gb * 16 + t];
  }
  __syncthreads();
  float ws = wsum[gb];
  for (int i = 0; i < 16; ++i) {
    int c = i * 256 + t;
    if (c >= IND) continue;
    const float* basep = (c < NG) ? sp : un;
    int cc = (c < NG) ? c : c - NG;
    float acc = 0.f;
#pragma unroll
    for (int k = 0; k < 16; ++k)
      acc += wv[k] * __logf(0.01f + basep[cb[k] + cc]);
    xb[(size_t)gb * IND + c] = f2bf(acc);
    if (g == 0) {
      float d = acc - ws * enc[(size_t)b * IND + c];
      db[(size_t)b * IND + c] = f2bf(d);
    }
  }
}

// ---------------- K=4000 projection GEMMs: relu(A @ W + bias), 3 segments in one grid ----------------
__global__ void __launch_bounds__(256) k_gemm256(
    const unsigned short* __restrict__ xb, const unsigned short* __restrict__ dbA,
    const unsigned short* __restrict__ ebA,
    const unsigned short* __restrict__ W1T, const unsigned short* __restrict__ WdT,
    const unsigned short* __restrict__ WrT,
    const float* __restrict__ b1, const float* __restrict__ bd, const float* __restrict__ br,
    float* __restrict__ h1, float* __restrict__ dout, float* __restrict__ rout) {
  __shared__ __align__(16) unsigned short a_tile[256 * 32];
  __shared__ __align__(16) unsigned short b_tile[64 * 32];
  int bz = blockIdx.x;
  const unsigned short *A, *WT;
  const float* bias;
  float* out;
  int rowbase;
  if (bz < 32)      { A = xb;  WT = W1T; bias = b1; out = h1;   rowbase = bz * 64; }
  else if (bz < 48) { A = dbA; WT = WdT; bias = bd; out = dout; rowbase = (bz - 32) * 64; }
  else              { A = ebA; WT = WrT; bias = br; out = rout; rowbase = (bz - 48) * 64; }

  const int t = threadIdx.x, wave = t >> 6, lane = t & 63;
  const int lrow = lane & 15, kgrp = lane >> 4;
  v4f acc[4][4];
#pragma unroll
  for (int i = 0; i < 4; i++)
#pragma unroll
    for (int j = 0; j < 4; j++) acc[i][j] = (v4f)0.f;

  for (int kt = 0; kt < 125; ++kt) {
#pragma unroll
    for (int j = 0; j < 4; ++j) {
      int c = (wave * 4 + j) * 64 + lane;
      int wcol = c >> 2, part = c & 3;
      async16(WT + (size_t)wcol * IND + kt * 32 + part * 8,
              (char*)a_tile + (size_t)c * 16);
    }
    {
      int c = wave * 64 + lane;
      int row = c >> 2, part = c & 3;
      async16(A + (size_t)(rowbase + row) * IND + kt * 32 + part * 8,
              (char*)b_tile + (size_t)c * 16);
    }
    __syncthreads();
    v8s bf[4];
#pragma unroll
    for (int nt = 0; nt < 4; nt++)
      bf[nt] = *reinterpret_cast<const v8s*>(&b_tile[(nt * 16 + lrow) * 32 + kgrp * 8]);
#pragma unroll
    for (int mt = 0; mt < 4; mt++) {
      v8s af = *reinterpret_cast<const v8s*>(&a_tile[(wave * 64 + mt * 16 + lrow) * 32 + kgrp * 8]);
#pragma unroll
      for (int nt = 0; nt < 4; nt++)
        acc[mt][nt] = __builtin_amdgcn_mfma_f32_16x16x32_bf16(af, bf[nt], acc[mt][nt], 0, 0, 0);
    }
    __syncthreads();
  }
#pragma unroll
  for (int mt = 0; mt < 4; mt++) {
#pragma unroll
    for (int r = 0; r < 4; r++) {
      int ocol = wave * 64 + mt * 16 + kgrp * 4 + r;
      float bs = bias[ocol];
#pragma unroll
      for (int nt = 0; nt < 4; nt++) {
        int row = nt * 16 + lrow;
        out[(size_t)(rowbase + row) * HDIM + ocol] = fmaxf(acc[mt][nt][r] + bs, 0.f);
      }
    }
  }
}

// ---------------- final: h@W2 + gate combine + LayerNorm + message gate ----------------
__global__ void __launch_bounds__(256) k_final(
    const float* __restrict__ h1, const float* __restrict__ dbuf, const float* __restrict__ rbuf,
    const float* __restrict__ W2, const float* __restrict__ b2,
    const float* __restrict__ mgate, const float* __restrict__ cgate,
    const float* __restrict__ gamma, const float* __restrict__ beta,
    float* __restrict__ out) {
  __shared__ float ha[256], hb[256];
  __shared__ float redbuf[8];
  int b = blockIdx.x, t = threadIdx.x;
  ha[t] = h1[b * 256 + t];
  hb[t] = h1[(1024 + b) * 256 + t];
  __syncthreads();
  float s1 = 0.f, s2 = 0.f;
#pragma unroll 8
  for (int j = 0; j < 256; ++j) {
    float w = W2[j * 256 + t];
    s1 = fmaf(ha[j], w, s1);
    s2 = fmaf(hb[j], w, s2);
  }
  float bb = b2[t];
  float h2a = fmaxf(s1 + bb, 0.f), h2b = fmaxf(s2 + bb, 0.f);
  float g = 1.f / (1.f + __expf(-cgate[t]));
  float p = g * h2a + (1.f - g) * h2b + dbuf[b * 256 + t] + rbuf[b * 256 + t];
  float sum = p, sumsq = p * p;
#pragma unroll
  for (int m = 1; m < 64; m <<= 1) {
    sum += __shfl_xor(sum, m);
    sumsq += __shfl_xor(sumsq, m);
  }
  int wave = t >> 6, lane = t & 63;
  if (lane == 0) { redbuf[wave] = sum; redbuf[4 + wave] = sumsq; }
  __syncthreads();
  sum = redbuf[0] + redbuf[1] + redbuf[2] + redbuf[3];
  sumsq = redbuf[4] + redbuf[5] + redbuf[6] + redbuf[7];
  float mu = sum * (1.f / 256.f);
  float var = sumsq * (1.f / 256.f) - mu * mu;
  float rs = rsqrtf(var + 1e-5f);
  float y = (p - mu) * rs * gamma[t] + beta[t];
  y *= 1.f / (1.f + __expf(-mgate[t]));
  out[(size_t)b * OUTW + 4000 + t] = y;
}

// ---------------- launch ----------------
extern "C" void kernel_launch(void* const* d_in, const int* in_sizes, int n_in,
                              void* d_out, int out_size, void* d_ws, size_t ws_size,
                              hipStream_t stream) {
  const float* enc  = (const float*)d_in[0];
  const int* ni1    = (const int*)d_in[1];
  const float* nw1  = (const float*)d_in[2];
  const int* ni2    = (const int*)d_in[3];
  const float* nw2  = (const float*)d_in[4];
  const float* sp   = (const float*)d_in[5];
  const float* un   = (const float*)d_in[6];
  const float* W1   = (const float*)d_in[7];
  const float* b1   = (const float*)d_in[8];
  const float* W2   = (const float*)d_in[9];
  const float* b2   = (const float*)d_in[10];
  const float* Wa1  = (const float*)d_in[11];
  const float* ba1  = (const float*)d_in[12];
  const float* Wa2  = (const float*)d_in[13];
  const float* ba2  = (const float*)d_in[14];
  const float* Wd   = (const float*)d_in[15];
  const float* bd   = (const float*)d_in[16];
  const float* Wr   = (const float*)d_in[17];
  const float* br   = (const float*)d_in[18];
  const float* gam  = (const float*)d_in[19];
  const float* bet  = (const float*)d_in[20];
  const float* mg   = (const float*)d_in[21];
  const float* cg   = (const float*)d_in[22];

  char* ws = (char*)d_ws;
  unsigned short* Wa1T = (unsigned short*)(ws + 0);         // 2,048,000
  unsigned short* W1T  = (unsigned short*)(ws + 2048000);   // 2,048,000
  unsigned short* WdT  = (unsigned short*)(ws + 4096000);   // 2,048,000
  unsigned short* WrT  = (unsigned short*)(ws + 6144000);   // 2,048,000
  unsigned short* XB   = (unsigned short*)(ws + 8192000);   // 16,384,000
  unsigned short* DB   = (unsigned short*)(ws + 24576000);  // 8,192,000
  unsigned short* EB   = (unsigned short*)(ws + 32768000);  // 8,192,000
  float* H1   = (float*)(ws + 40960000);                    // 2,097,152
  float* DBUF = (float*)(ws + 43057152);                    // 1,048,576
  float* RBUF = (float*)(ws + 44105728);                    // 1,048,576
  float* LOG  = (float*)(ws + 45154304);                    // 131,072
  float* WN   = (float*)(ws + 45285376);                    // 131,072
  float* WSUM = (float*)(ws + 45416448);                    // 8,192  (total ~45.4 MB)

  float* out = (float*)d_out;

  hipLaunchKernelGGL(k_transpose, dim3(125, 8, 4), dim3(32, 8), 0, stream,
                     W1, Wa1, Wd, Wr, (unsigned short*)ws);
  hipLaunchKernelGGL(k_enc_copy, dim3(16, 1024), dim3(256), 0, stream, enc, out, EB);
  hipLaunchKernelGGL(k_logits, dim3(512), dim3(256), 0, stream,
                     ni1, ni2, sp, un, Wa1T, ba1, Wa2, ba2, LOG);
  hipLaunchKernelGGL(k_softmax, dim3(128), dim3(256), 0, stream, LOG, nw1, nw2, WN, WSUM);
  hipLaunchKernelGGL(k_wsum, dim3(2048), dim3(256), 0, stream,
                     ni1, ni2, sp, un, enc, WN, WSUM, XB, DB);
  hipLaunchKernelGGL(k_gemm256, dim3(64), dim3(256), 0, stream,
                     XB, DB, EB, W1T, WdT, WrT, b1, bd, br, H1, DBUF, RBUF);
  hipLaunchKernelGGL(k_final, dim3(1024), dim3(256), 0, stream,
                     H1, DBUF, RBUF, W2, b2, mg, cg, gam, bet, out);
}

// Round 2
// 1044.548 us; speedup vs baseline: 1.1209x; 1.1209x over previous
//
#include <hip/hip_runtime.h>
#include <cstdint>
#include <cstddef>

typedef short v8s __attribute__((ext_vector_type(8)));
typedef float v4f __attribute__((ext_vector_type(4)));

#define NG   2000
#define IND  4000
#define HDIM 256
#define OUTW 4256   // IND + HDIM

// ---------------- helpers ----------------
__device__ __forceinline__ unsigned short f2bf(float f) {
  unsigned a = __builtin_bit_cast(unsigned, f);
  a += 0x7fffu + ((a >> 16) & 1u);
  return (unsigned short)(a >> 16);
}
__device__ __forceinline__ unsigned pk2bf(float lo, float hi) {
  unsigned a = __builtin_bit_cast(unsigned, lo);
  unsigned b = __builtin_bit_cast(unsigned, hi);
  a += 0x7fffu + ((a >> 16) & 1u);
  b += 0x7fffu + ((b >> 16) & 1u);
  return (a >> 16) | (b & 0xffff0000u);
}
__device__ __forceinline__ void async16(const void* g, void* l) {
  __builtin_amdgcn_global_load_lds(
      (const __attribute__((address_space(1))) unsigned int*)g,
      (__attribute__((address_space(3))) unsigned int*)l, 16, 0, 0);
}

// ---------------- prep: transpose 4 weight matrices [4000,256] -> bf16 [256,4000] ----------------
__global__ void k_transpose(const float* __restrict__ w1, const float* __restrict__ wa1,
                            const float* __restrict__ wd, const float* __restrict__ wr,
                            unsigned short* __restrict__ ws0) {
  __shared__ float tl[32][33];
  int mat = blockIdx.z;
  const float* src = (mat == 0) ? wa1 : (mat == 1) ? w1 : (mat == 2) ? wd : wr;
  unsigned short* dst = ws0 + (size_t)mat * 1024000;  // 2,048,000 B each
  int j0 = blockIdx.x * 32, c0 = blockIdx.y * 32;
  int tx = threadIdx.x, ty = threadIdx.y;
  for (int jj = ty; jj < 32; jj += 8)
    tl[jj][tx] = src[(size_t)(j0 + jj) * HDIM + c0 + tx];
  __syncthreads();
  for (int cc = ty; cc < 32; cc += 8)
    dst[(size_t)(c0 + cc) * IND + j0 + tx] = f2bf(tl[tx][cc]);
}

// ---------------- enc copy to out + bf16 cast ----------------
__global__ void k_enc_copy(const float* __restrict__ enc, float* __restrict__ out,
                           unsigned short* __restrict__ eb) {
  int c = blockIdx.x * 256 + threadIdx.x;
  int b = blockIdx.y;
  if (c < IND) {
    float v = enc[(size_t)b * IND + c];
    out[(size_t)b * OUTW + c] = v;
    eb[(size_t)b * IND + c] = f2bf(v);
  }
}

// ---------------- attention logits: fused gather+log + MFMA GEMM + tanh·Wa2 ----------------
// grid 512 (64 rows each), block 256. C[m=wcol 256][n=row 64], wave w owns wcols [w*64, w*64+64)
// Pipelined: iter kt+1's gather loads issued in the store/asyncA window so B-latency
// and A-DMA latency drain at the same barrier (max, not sum).
__global__ void __launch_bounds__(256) k_logits(
    const int* __restrict__ nidx1, const int* __restrict__ nidx2,
    const float* __restrict__ sp, const float* __restrict__ un,
    const unsigned short* __restrict__ Wa1T,
    const float* __restrict__ ba1, const float* __restrict__ Wa2,
    const float* __restrict__ ba2, float* __restrict__ logits) {
  __shared__ __align__(16) unsigned short a_tile[256 * 32];
  __shared__ __align__(16) unsigned short b_tile[64 * 32];
  __shared__ int scell[64];
  __shared__ float red[4][64];

  const int t = threadIdx.x;
  const int wave = t >> 6, lane = t & 63;
  const int row_base = blockIdx.x * 64;

  if (t < 64) {
    int r = row_base + t;
    scell[t] = (r < 16384) ? nidx1[r] : nidx2[r - 16384];
  }
  __syncthreads();

  const int lrow = lane & 15, kgrp = lane >> 4;
  const int brow = t >> 2, bpart = t & 3;
  const size_t cellbase = (size_t)scell[brow] * NG;

  v4f acc[4][4];
#pragma unroll
  for (int i = 0; i < 4; i++)
#pragma unroll
    for (int j = 0; j < 4; j++) acc[i][j] = (v4f)0.f;

  // prologue: load B slice for kt=0
  float4 c0, c1;
  {
    int col0 = bpart * 8;
    const float* src = sp + cellbase + col0;  // kt=0: col0<2000 always
    c0 = reinterpret_cast<const float4*>(src)[0];
    c1 = reinterpret_cast<const float4*>(src)[1];
  }

  for (int kt = 0; kt < 125; ++kt) {
    uint4 pk;
    pk.x = pk2bf(__logf(0.01f + c0.x), __logf(0.01f + c0.y));
    pk.y = pk2bf(__logf(0.01f + c0.z), __logf(0.01f + c0.w));
    pk.z = pk2bf(__logf(0.01f + c1.x), __logf(0.01f + c1.y));
    pk.w = pk2bf(__logf(0.01f + c1.z), __logf(0.01f + c1.w));
    __syncthreads();  // prev iter's MFMA done reading LDS
    // issue next iter's gather (drains at the 2nd barrier together with asyncA)
    float4 n0, n1;
    if (kt < 124) {
      int col0 = (kt + 1) * 32 + bpart * 8;
      const float* src = (col0 < NG) ? (sp + cellbase + col0) : (un + cellbase + (col0 - NG));
      n0 = reinterpret_cast<const float4*>(src)[0];
      n1 = reinterpret_cast<const float4*>(src)[1];
    }
    reinterpret_cast<uint4*>(b_tile)[t] = pk;
    // A tile: Wa1T[256][kt*32..+32] via async DMA (1024 16B chunks)
#pragma unroll
    for (int j = 0; j < 4; ++j) {
      int c = (wave * 4 + j) * 64 + lane;
      int wcol = c >> 2, part = c & 3;
      async16(Wa1T + (size_t)wcol * IND + kt * 32 + part * 8,
              (char*)a_tile + (size_t)c * 16);
    }
    __syncthreads();
    v8s bf[4];
#pragma unroll
    for (int nt = 0; nt < 4; nt++)
      bf[nt] = *reinterpret_cast<const v8s*>(&b_tile[(nt * 16 + lrow) * 32 + kgrp * 8]);
#pragma unroll
    for (int mt = 0; mt < 4; mt++) {
      v8s af = *reinterpret_cast<const v8s*>(&a_tile[(wave * 64 + mt * 16 + lrow) * 32 + kgrp * 8]);
#pragma unroll
      for (int nt = 0; nt < 4; nt++)
        acc[mt][nt] = __builtin_amdgcn_mfma_f32_16x16x32_bf16(af, bf[nt], acc[mt][nt], 0, 0, 0);
    }
    if (kt < 124) { c0 = n0; c1 = n1; }
  }

  // epilogue: logit[row] = sum_wcol tanh(h + ba1)·Wa2 + ba2
  float partial[4] = {0.f, 0.f, 0.f, 0.f};
#pragma unroll
  for (int mt = 0; mt < 4; mt++) {
#pragma unroll
    for (int r = 0; r < 4; r++) {
      int wcol = wave * 64 + mt * 16 + kgrp * 4 + r;
      float bb = ba1[wcol], wv = Wa2[wcol];
#pragma unroll
      for (int nt = 0; nt < 4; nt++) {
        float h = acc[mt][nt][r] + bb;
        float th = 1.f - 2.f / (1.f + __expf(2.f * h));  // NaN/overflow-safe tanh
        partial[nt] += th * wv;
      }
    }
  }
#pragma unroll
  for (int nt = 0; nt < 4; nt++) {
    float p = partial[nt];
    p += __shfl_xor(p, 16);
    p += __shfl_xor(p, 32);
    if (lane < 16) red[wave][nt * 16 + lane] = p;
  }
  __syncthreads();
  if (t < 64)
    logits[row_base + t] = red[0][t] + red[1][t] + red[2][t] + red[3][t] + ba2[0];
}

// ---------------- fused softmax + weighted sum gather: x (bf16), diff = x - wsum*enc (bf16) ----------------
__global__ void __launch_bounds__(256) k_wsum(
    const int* __restrict__ nidx1, const int* __restrict__ nidx2,
    const float* __restrict__ sp, const float* __restrict__ un,
    const float* __restrict__ enc,
    const float* __restrict__ logits,
    const float* __restrict__ nw1, const float* __restrict__ nw2,
    unsigned short* __restrict__ xb, unsigned short* __restrict__ db) {
  __shared__ size_t cb[16];
  __shared__ float wv[16];
  __shared__ float wsum_s;
  int gb = blockIdx.x, t = threadIdx.x;
  int g = gb >> 10, b = gb & 1023;
  if (t < 16) {
    int cell = (g == 0 ? nidx1 : nidx2)[b * 16 + t];
    cb[t] = (size_t)cell * NG;
    float lg = logits[gb * 16 + t];
    float mx = lg;
#pragma unroll
    for (int m = 1; m < 16; m <<= 1) mx = fmaxf(mx, __shfl_xor(mx, m));
    float e = __expf(lg - mx);
    float s = e;
#pragma unroll
    for (int m = 1; m < 16; m <<= 1) s += __shfl_xor(s, m);
    float att = e / s;
    float nw = (g == 0) ? nw1[b * 16 + t] : nw2[b * 16 + t];
    float w = nw * att;
    float S = w;
#pragma unroll
    for (int m = 1; m < 16; m <<= 1) S += __shfl_xor(S, m);
    wv[t] = w / (S + 1e-12f);
    if (t == 0) wsum_s = S / (S + 1e-12f);
  }
  __syncthreads();
  float ws = wsum_s;
  for (int i = 0; i < 16; ++i) {
    int c = i * 256 + t;
    if (c >= IND) continue;
    const float* basep = (c < NG) ? sp : un;
    int cc = (c < NG) ? c : c - NG;
    float acc = 0.f;
#pragma unroll
    for (int k = 0; k < 16; ++k)
      acc += wv[k] * __logf(0.01f + basep[cb[k] + cc]);
    xb[(size_t)gb * IND + c] = f2bf(acc);
    if (g == 0) {
      float d = acc - ws * enc[(size_t)b * IND + c];
      db[(size_t)b * IND + c] = f2bf(d);
    }
  }
}

// ---------------- K=4000 projection GEMMs, K-split x4: raw partial sums into P ----------------
// grid 256: chunk = bz>>6 (K-iters [0,32,63,94,125]), tile = bz&63 (3 segments x 64-row tiles)
__global__ void __launch_bounds__(256) k_gemm256(
    const unsigned short* __restrict__ xb, const unsigned short* __restrict__ dbA,
    const unsigned short* __restrict__ ebA,
    const unsigned short* __restrict__ W1T, const unsigned short* __restrict__ WdT,
    const unsigned short* __restrict__ WrT,
    float* __restrict__ P) {
  __shared__ __align__(16) unsigned short a_tile[256 * 32];
  __shared__ __align__(16) unsigned short b_tile[64 * 32];
  int bz = blockIdx.x;
  int chunk = bz >> 6, tile = bz & 63;
  const int kstart[5] = {0, 32, 63, 94, 125};
  int k0 = kstart[chunk], k1 = kstart[chunk + 1];

  const unsigned short *A, *WT;
  int rowbase, growbase;
  if (tile < 32)      { A = xb;  WT = W1T; rowbase = tile * 64;        growbase = rowbase; }
  else if (tile < 48) { A = dbA; WT = WdT; rowbase = (tile - 32) * 64; growbase = 2048 + rowbase; }
  else                { A = ebA; WT = WrT; rowbase = (tile - 48) * 64; growbase = 3072 + rowbase; }

  const int t = threadIdx.x, wave = t >> 6, lane = t & 63;
  const int lrow = lane & 15, kgrp = lane >> 4;
  v4f acc[4][4];
#pragma unroll
  for (int i = 0; i < 4; i++)
#pragma unroll
    for (int j = 0; j < 4; j++) acc[i][j] = (v4f)0.f;

  for (int kt = k0; kt < k1; ++kt) {
#pragma unroll
    for (int j = 0; j < 4; ++j) {
      int c = (wave * 4 + j) * 64 + lane;
      int wcol = c >> 2, part = c & 3;
      async16(WT + (size_t)wcol * IND + kt * 32 + part * 8,
              (char*)a_tile + (size_t)c * 16);
    }
    {
      int c = wave * 64 + lane;
      int row = c >> 2, part = c & 3;
      async16(A + (size_t)(rowbase + row) * IND + kt * 32 + part * 8,
              (char*)b_tile + (size_t)c * 16);
    }
    __syncthreads();
    v8s bf[4];
#pragma unroll
    for (int nt = 0; nt < 4; nt++)
      bf[nt] = *reinterpret_cast<const v8s*>(&b_tile[(nt * 16 + lrow) * 32 + kgrp * 8]);
#pragma unroll
    for (int mt = 0; mt < 4; mt++) {
      v8s af = *reinterpret_cast<const v8s*>(&a_tile[(wave * 64 + mt * 16 + lrow) * 32 + kgrp * 8]);
#pragma unroll
      for (int nt = 0; nt < 4; nt++)
        acc[mt][nt] = __builtin_amdgcn_mfma_f32_16x16x32_bf16(af, bf[nt], acc[mt][nt], 0, 0, 0);
    }
    __syncthreads();
  }
#pragma unroll
  for (int mt = 0; mt < 4; mt++) {
#pragma unroll
    for (int r = 0; r < 4; r++) {
      int ocol = wave * 64 + mt * 16 + kgrp * 4 + r;
#pragma unroll
      for (int nt = 0; nt < 4; nt++) {
        int row = nt * 16 + lrow;
        P[((size_t)chunk * 4096 + growbase + row) * HDIM + ocol] = acc[mt][nt][r];
      }
    }
  }
}

// ---------------- final: chunk-reduce + bias/relu + h@W2 + gate combine + LayerNorm ----------------
__global__ void __launch_bounds__(256) k_final(
    const float* __restrict__ P,
    const float* __restrict__ b1, const float* __restrict__ bd, const float* __restrict__ br,
    const float* __restrict__ W2, const float* __restrict__ b2,
    const float* __restrict__ mgate, const float* __restrict__ cgate,
    const float* __restrict__ gamma, const float* __restrict__ beta,
    float* __restrict__ out) {
  __shared__ float ha[256], hb[256];
  __shared__ float redbuf[8];
  int b = blockIdx.x, t = threadIdx.x;
  float sa = 0.f, sb = 0.f, sd = 0.f, sr = 0.f;
#pragma unroll
  for (int c = 0; c < 4; ++c) {
    const float* base = P + (size_t)c * 4096 * HDIM;
    sa += base[(size_t)b * HDIM + t];
    sb += base[(size_t)(1024 + b) * HDIM + t];
    sd += base[(size_t)(2048 + b) * HDIM + t];
    sr += base[(size_t)(3072 + b) * HDIM + t];
  }
  ha[t] = fmaxf(sa + b1[t], 0.f);
  hb[t] = fmaxf(sb + b1[t], 0.f);
  float dv = fmaxf(sd + bd[t], 0.f);
  float rv = fmaxf(sr + br[t], 0.f);
  __syncthreads();
  float s1 = 0.f, s2 = 0.f;
#pragma unroll 8
  for (int j = 0; j < 256; ++j) {
    float w = W2[j * 256 + t];
    s1 = fmaf(ha[j], w, s1);
    s2 = fmaf(hb[j], w, s2);
  }
  float bb = b2[t];
  float h2a = fmaxf(s1 + bb, 0.f), h2b = fmaxf(s2 + bb, 0.f);
  float g = 1.f / (1.f + __expf(-cgate[t]));
  float p = g * h2a + (1.f - g) * h2b + dv + rv;
  float sum = p, sumsq = p * p;
#pragma unroll
  for (int m = 1; m < 64; m <<= 1) {
    sum += __shfl_xor(sum, m);
    sumsq += __shfl_xor(sumsq, m);
  }
  int wave = t >> 6, lane = t & 63;
  if (lane == 0) { redbuf[wave] = sum; redbuf[4 + wave] = sumsq; }
  __syncthreads();
  sum = redbuf[0] + redbuf[1] + redbuf[2] + redbuf[3];
  sumsq = redbuf[4] + redbuf[5] + redbuf[6] + redbuf[7];
  float mu = sum * (1.f / 256.f);
  float var = sumsq * (1.f / 256.f) - mu * mu;
  float rs = rsqrtf(var + 1e-5f);
  float y = (p - mu) * rs * gamma[t] + beta[t];
  y *= 1.f / (1.f + __expf(-mgate[t]));
  out[(size_t)b * OUTW + 4000 + t] = y;
}

// ---------------- launch ----------------
extern "C" void kernel_launch(void* const* d_in, const int* in_sizes, int n_in,
                              void* d_out, int out_size, void* d_ws, size_t ws_size,
                              hipStream_t stream) {
  const float* enc  = (const float*)d_in[0];
  const int* ni1    = (const int*)d_in[1];
  const float* nw1  = (const float*)d_in[2];
  const int* ni2    = (const int*)d_in[3];
  const float* nw2  = (const float*)d_in[4];
  const float* sp   = (const float*)d_in[5];
  const float* un   = (const float*)d_in[6];
  const float* W1   = (const float*)d_in[7];
  const float* b1   = (const float*)d_in[8];
  const float* W2   = (const float*)d_in[9];
  const float* b2   = (const float*)d_in[10];
  const float* Wa1  = (const float*)d_in[11];
  const float* ba1  = (const float*)d_in[12];
  const float* Wa2  = (const float*)d_in[13];
  const float* ba2  = (const float*)d_in[14];
  const float* Wd   = (const float*)d_in[15];
  const float* bd   = (const float*)d_in[16];
  const float* Wr   = (const float*)d_in[17];
  const float* br   = (const float*)d_in[18];
  const float* gam  = (const float*)d_in[19];
  const float* bet  = (const float*)d_in[20];
  const float* mg   = (const float*)d_in[21];
  const float* cg   = (const float*)d_in[22];

  char* ws = (char*)d_ws;
  unsigned short* Wa1T = (unsigned short*)(ws + 0);         // 2,048,000
  unsigned short* W1T  = (unsigned short*)(ws + 2048000);   // 2,048,000
  unsigned short* WdT  = (unsigned short*)(ws + 4096000);   // 2,048,000
  unsigned short* WrT  = (unsigned short*)(ws + 6144000);   // 2,048,000
  unsigned short* XB   = (unsigned short*)(ws + 8192000);   // 16,384,000
  unsigned short* DB   = (unsigned short*)(ws + 24576000);  // 8,192,000
  unsigned short* EB   = (unsigned short*)(ws + 32768000);  // 8,192,000
  float* P    = (float*)(ws + 40960000);                    // 16,777,216 (4 chunks x 4096 x 256)
  float* LOG  = (float*)(ws + 57737216);                    // 131,072   (total ~57.9 MB)

  float* out = (float*)d_out;

  hipLaunchKernelGGL(k_transpose, dim3(125, 8, 4), dim3(32, 8), 0, stream,
                     W1, Wa1, Wd, Wr, (unsigned short*)ws);
  hipLaunchKernelGGL(k_enc_copy, dim3(16, 1024), dim3(256), 0, stream, enc, out, EB);
  hipLaunchKernelGGL(k_logits, dim3(512), dim3(256), 0, stream,
                     ni1, ni2, sp, un, Wa1T, ba1, Wa2, ba2, LOG);
  hipLaunchKernelGGL(k_wsum, dim3(2048), dim3(256), 0, stream,
                     ni1, ni2, sp, un, enc, LOG, nw1, nw2, XB, DB);
  hipLaunchKernelGGL(k_gemm256, dim3(256), dim3(256), 0, stream,
                     XB, DB, EB, W1T, WdT, WrT, P);
  hipLaunchKernelGGL(k_final, dim3(1024), dim3(256), 0, stream,
                     P, b1, bd, br, W2, b2, mg, cg, gam, bet, out);
}